// Round 13
// baseline (184.071 us; speedup 1.0000x reference)
//
#include <hip/hip_runtime.h>

#define B 32
#define N 128
#define DD 32
#define H 64
#define C 10

typedef unsigned short bfu;   // raw bf16 storage
typedef __attribute__((ext_vector_type(8))) short bf16x8;  // 8 bf16 (4 VGPRs)
typedef __attribute__((ext_vector_type(4))) float f32x4;   // MFMA accumulator

#define MFMA16 __builtin_amdgcn_mfma_f32_16x16x32_bf16

__device__ __forceinline__ float b2f(bfu v) {
    union { unsigned u; float f; } x; x.u = ((unsigned)v) << 16; return x.f;
}
__device__ __forceinline__ bfu f2b(float f) {
    union { __bf16 b; bfu u; } c; c.b = (__bf16)f; return c.u;
}
__device__ __forceinline__ float lo2f(unsigned u) {
    union { unsigned x; float f; } c; c.x = u << 16; return c.f;
}
__device__ __forceinline__ float hi2f(unsigned u) {
    union { unsigned x; float f; } c; c.x = u & 0xffff0000u; return c.f;
}
__device__ __forceinline__ void up8(uint4 u, float* f) {
    f[0] = lo2f(u.x); f[1] = hi2f(u.x); f[2] = lo2f(u.y); f[3] = hi2f(u.y);
    f[4] = lo2f(u.z); f[5] = hi2f(u.z); f[6] = lo2f(u.w); f[7] = hi2f(u.w);
}
__device__ __forceinline__ unsigned pk2(float a, float b) {
    return (unsigned)f2b(a) | ((unsigned)f2b(b) << 16);
}

// ---------------- fused prep: blocks [0,512) convert adj; [512,522) transpose weights
struct WT { const float* src[10]; bfu* dst[10]; int K[10]; };
__global__ __launch_bounds__(256) void prep_all(const float* __restrict__ adj,
                                                bfu* __restrict__ acb,
                                                bfu* __restrict__ adjf, WT p) {
    int blk = blockIdx.x;
    if (blk < 512) {
        int idx = blk * 256 + threadIdx.x;
        float4 v = ((const float4*)adj)[idx];
        int e0 = idx * 4;
        int w = e0 & 127;
        int i = (e0 >> 7) & 127;
        ushort4 o;
        o.x = f2b((i == w    ) ? 0.f : v.x);
        o.y = f2b((i == w + 1) ? 0.f : v.y);
        o.z = f2b((i == w + 2) ? 0.f : v.z);
        o.w = f2b((i == w + 3) ? 0.f : v.w);
        ((ushort4*)acb)[idx] = o;
        ushort4 oF;
        oF.x = f2b(v.x); oF.y = f2b(v.y); oF.z = f2b(v.z); oF.w = f2b(v.w);
        ((ushort4*)adjf)[idx] = oF;
    } else {
        int m = blk - 512;
        const float* S = p.src[m];
        bfu* D = p.dst[m];
        int K = p.K[m];
        int t = threadIdx.x; int d = t & 63;
        for (int k = t >> 6; k < K; k += 4)
            D[d * K + k] = f2b(S[k * 64 + d]);
    }
}

// ---------------- fused front-end: per-batch GNN layers + emb1 + U/V projections
__global__ __launch_bounds__(256) void gnn_front(const float* __restrict__ x,
                                                 const bfu* __restrict__ adjf,
                                                 const bfu* __restrict__ w11t,
                                                 const float* __restrict__ b11,
                                                 const bfu* __restrict__ w12t,
                                                 const float* __restrict__ b12,
                                                 const bfu* __restrict__ w21t,
                                                 const float* __restrict__ b21,
                                                 const bfu* __restrict__ w22t,
                                                 const float* __restrict__ b22,
                                                 const bfu* __restrict__ u1t,
                                                 const bfu* __restrict__ v1t,
                                                 const bfu* __restrict__ u2t,
                                                 const bfu* __restrict__ v2t,
                                                 bfu* __restrict__ U1,
                                                 bfu* __restrict__ V1,
                                                 bfu* __restrict__ U2,
                                                 bfu* __restrict__ V2,
                                                 float* __restrict__ emb1) {
    int b = blockIdx.x;
    int t = threadIdx.x, lane = t & 63, wid = t >> 6;
    int l16 = lane & 15, g4 = lane >> 4;
    __shared__ bfu Af[128 * 136];
    __shared__ bfu Yt[64 * 136];
    __shared__ bfu Hs[128 * 72];
    __shared__ bfu Xs[128 * 40];
    __shared__ float red[16][64];
    {
        int i = t >> 1, half = t & 1;
        const uint4* src = (const uint4*)(adjf + ((size_t)b * N + i) * N + half * 64);
        uint4* dst = (uint4*)&Af[i * 136 + half * 64];
#pragma unroll
        for (int q = 0; q < 8; ++q) dst[q] = src[q];
        const float4* sx = (const float4*)(x + ((size_t)b * N + i) * DD + half * 16);
        float xv[16];
        *(float4*)&xv[0]  = sx[0]; *(float4*)&xv[4]  = sx[1];
        *(float4*)&xv[8]  = sx[2]; *(float4*)&xv[12] = sx[3];
        unsigned q[8];
#pragma unroll
        for (int e = 0; e < 8; ++e) q[e] = pk2(xv[2 * e], xv[2 * e + 1]);
        uint4* dx = (uint4*)&Xs[i * 40 + half * 16];
        dx[0] = make_uint4(q[0], q[1], q[2], q[3]);
        dx[1] = make_uint4(q[4], q[5], q[6], q[7]);
    }
    __syncthreads();
    f32x4 a1[2][4], a2[2][4];
#define ZERO(A) _Pragma("unroll") for (int m = 0; m < 2; ++m) _Pragma("unroll") for (int n = 0; n < 4; ++n) A[m][n] = (f32x4){0.f,0.f,0.f,0.f};
    ZERO(a1); ZERO(a2);
    {
        int k0 = g4 * 8;
        bf16x8 bw1[4], bw2[4];
#pragma unroll
        for (int n = 0; n < 4; ++n) {
            bw1[n] = *(const bf16x8*)&w11t[(l16 + 16 * n) * 32 + k0];
            bw2[n] = *(const bf16x8*)&w12t[(l16 + 16 * n) * 32 + k0];
        }
#pragma unroll
        for (int m = 0; m < 2; ++m) {
            bf16x8 afr = *(const bf16x8*)&Xs[(wid * 32 + m * 16 + l16) * 40 + k0];
#pragma unroll
            for (int n = 0; n < 4; ++n) {
                a1[m][n] = MFMA16(afr, bw1[n], a1[m][n], 0, 0, 0);
                a2[m][n] = MFMA16(afr, bw2[n], a2[m][n], 0, 0, 0);
            }
        }
    }
    {
        float bb[4];
#pragma unroll
        for (int n = 0; n < 4; ++n) bb[n] = b12[l16 + 16 * n];
#pragma unroll
        for (int m = 0; m < 2; ++m)
#pragma unroll
            for (int n = 0; n < 4; ++n) {
                uint2 q;
                q.x = pk2(a2[m][n][0] + bb[n], a2[m][n][1] + bb[n]);
                q.y = pk2(a2[m][n][2] + bb[n], a2[m][n][3] + bb[n]);
                *(uint2*)&Yt[(l16 + 16 * n) * 136 + wid * 32 + m * 16 + g4 * 4] = q;
            }
    }
    __syncthreads();
    ZERO(a2);
#pragma unroll
    for (int ks = 0; ks < 4; ++ks) {
        int k0 = ks * 32 + g4 * 8;
        bf16x8 bfr[4];
#pragma unroll
        for (int n = 0; n < 4; ++n) bfr[n] = *(const bf16x8*)&Yt[(l16 + 16 * n) * 136 + k0];
#pragma unroll
        for (int m = 0; m < 2; ++m) {
            bf16x8 afr = *(const bf16x8*)&Af[(wid * 32 + m * 16 + l16) * 136 + k0];
#pragma unroll
            for (int n = 0; n < 4; ++n) a2[m][n] = MFMA16(afr, bfr[n], a2[m][n], 0, 0, 0);
        }
    }
    {
        float bb[4];
#pragma unroll
        for (int n = 0; n < 4; ++n) bb[n] = b11[l16 + 16 * n];
#pragma unroll
        for (int m = 0; m < 2; ++m)
#pragma unroll
            for (int n = 0; n < 4; ++n)
#pragma unroll
                for (int r = 0; r < 4; ++r)
                    Hs[(wid * 32 + m * 16 + g4 * 4 + r) * 72 + l16 + 16 * n] =
                        f2b(fmaxf(a1[m][n][r] + bb[n] + a2[m][n][r], 0.f));
    }
    __syncthreads();
    ZERO(a1); ZERO(a2);
#pragma unroll
    for (int ks = 0; ks < 2; ++ks) {
        int k0 = ks * 32 + g4 * 8;
        bf16x8 bw1[4], bw2[4];
#pragma unroll
        for (int n = 0; n < 4; ++n) {
            bw1[n] = *(const bf16x8*)&w21t[(l16 + 16 * n) * 64 + k0];
            bw2[n] = *(const bf16x8*)&w22t[(l16 + 16 * n) * 64 + k0];
        }
#pragma unroll
        for (int m = 0; m < 2; ++m) {
            bf16x8 afr = *(const bf16x8*)&Hs[(wid * 32 + m * 16 + l16) * 72 + k0];
#pragma unroll
            for (int n = 0; n < 4; ++n) {
                a1[m][n] = MFMA16(afr, bw1[n], a1[m][n], 0, 0, 0);
                a2[m][n] = MFMA16(afr, bw2[n], a2[m][n], 0, 0, 0);
            }
        }
    }
    {
        float bb[4];
#pragma unroll
        for (int n = 0; n < 4; ++n) bb[n] = b22[l16 + 16 * n];
#pragma unroll
        for (int m = 0; m < 2; ++m)
#pragma unroll
            for (int n = 0; n < 4; ++n) {
                uint2 q;
                q.x = pk2(a2[m][n][0] + bb[n], a2[m][n][1] + bb[n]);
                q.y = pk2(a2[m][n][2] + bb[n], a2[m][n][3] + bb[n]);
                *(uint2*)&Yt[(l16 + 16 * n) * 136 + wid * 32 + m * 16 + g4 * 4] = q;
            }
    }
    __syncthreads();
    ZERO(a2);
#pragma unroll
    for (int ks = 0; ks < 4; ++ks) {
        int k0 = ks * 32 + g4 * 8;
        bf16x8 bfr[4];
#pragma unroll
        for (int n = 0; n < 4; ++n) bfr[n] = *(const bf16x8*)&Yt[(l16 + 16 * n) * 136 + k0];
#pragma unroll
        for (int m = 0; m < 2; ++m) {
            bf16x8 afr = *(const bf16x8*)&Af[(wid * 32 + m * 16 + l16) * 136 + k0];
#pragma unroll
            for (int n = 0; n < 4; ++n) a2[m][n] = MFMA16(afr, bfr[n], a2[m][n], 0, 0, 0);
        }
    }
    {
        float bb[4], s[4] = {0.f, 0.f, 0.f, 0.f};
#pragma unroll
        for (int n = 0; n < 4; ++n) bb[n] = b21[l16 + 16 * n];
#pragma unroll
        for (int m = 0; m < 2; ++m)
#pragma unroll
            for (int n = 0; n < 4; ++n)
#pragma unroll
                for (int r = 0; r < 4; ++r) {
                    float v = fmaxf(a1[m][n][r] + bb[n] + a2[m][n][r], 0.f);
                    Hs[(wid * 32 + m * 16 + g4 * 4 + r) * 72 + l16 + 16 * n] = f2b(v);
                    s[n] += v;
                }
#pragma unroll
        for (int n = 0; n < 4; ++n) red[wid * 4 + g4][l16 + 16 * n] = s[n];
    }
    __syncthreads();
    if (t < 64) {
        float e = 0.f;
#pragma unroll
        for (int q = 0; q < 16; ++q) e += red[q][t];
        emb1[b * 64 + t] = e;
    }
    const bfu* wts[4] = {u1t, v1t, u2t, v2t};
    bfu* outs[4] = {U1, V1, U2, V2};
#pragma unroll
    for (int o = 0; o < 4; ++o) {
        ZERO(a1);
#pragma unroll
        for (int ks = 0; ks < 2; ++ks) {
            int k0 = ks * 32 + g4 * 8;
            bf16x8 bw[4];
#pragma unroll
            for (int n = 0; n < 4; ++n)
                bw[n] = *(const bf16x8*)&wts[o][(l16 + 16 * n) * 64 + k0];
#pragma unroll
            for (int m = 0; m < 2; ++m) {
                bf16x8 afr = *(const bf16x8*)&Hs[(wid * 32 + m * 16 + l16) * 72 + k0];
#pragma unroll
                for (int n = 0; n < 4; ++n) a1[m][n] = MFMA16(afr, bw[n], a1[m][n], 0, 0, 0);
            }
        }
#pragma unroll
        for (int m = 0; m < 2; ++m)
#pragma unroll
            for (int n = 0; n < 4; ++n)
#pragma unroll
                for (int r = 0; r < 4; ++r)
                    Af[(wid * 32 + m * 16 + g4 * 4 + r) * 72 + l16 + 16 * n] = f2b(a1[m][n][r]);
        __syncthreads();
        {
            int i = t >> 1, half = t & 1;
            const uint4* src = (const uint4*)&Af[i * 72 + half * 32];
            uint4* dst = (uint4*)(outs[o] + ((size_t)b * N + i) * H + half * 32);
            dst[0] = src[0]; dst[1] = src[1]; dst[2] = src[2]; dst[3] = src[3];
        }
        __syncthreads();
    }
#undef ZERO
}

// ---------------- XCD-aware bijective swizzle (grid divisible by 8)
__device__ __forceinline__ int xcd_swz(int wg, int nwg) {
    return (wg & 7) * (nwg >> 3) + (wg >> 3);
}

// ---------------- t1: T1[bl,j,i,d] = sum_w ac[b,i,w]*G[j,w,d]  via MFMA
__global__ __launch_bounds__(256) void t1_mfma(const bfu* __restrict__ U2,
                                               const bfu* __restrict__ V2,
                                               const bfu* __restrict__ acb,
                                               const float* __restrict__ wl,
                                               const float* __restrict__ bv,
                                               bfu* __restrict__ T, int b0) {
    int wid2 = xcd_swz(blockIdx.x, gridDim.x);
    int bl = wid2 >> 7, j = wid2 & 127;
    int b = b0 + bl;
    int t = threadIdx.x, lane = t & 63, wid = t >> 6;
    int l16 = lane & 15, g4 = lane >> 4;
    __shared__ bfu lds[128 * 72];
    __shared__ float arl[N];
    const bfu* arow = acb + ((size_t)b * N + j) * N;
    if (t < N) arl[t] = b2f(arow[t]);
    __syncthreads();
    {
        int d = lane;
        const bfu* U2b = U2 + (size_t)b * N * H;
        const bfu* V2b = V2 + (size_t)b * N * H;
        float wld = wl[d], bvd = bv[d];
        float UjB = b2f(U2b[j * H + d]) + bvd, VjB = b2f(V2b[j * H + d]) + bvd;
#pragma unroll
        for (int p = 0; p < 4; ++p) {
            int w0 = p * 32 + wid * 8;
            unsigned q[4];
#pragma unroll
            for (int rr = 0; rr < 4; ++rr) {
                float g01[2];
#pragma unroll
                for (int hh = 0; hh < 2; ++hh) {
                    int w = w0 + rr * 2 + hh;
                    float a = arl[w];
                    float rvar = (w < j) ? b2f(U2b[w * H + d]) : b2f(V2b[w * H + d]);
                    float base = (w < j) ? VjB : UjB;
                    g01[hh] = rvar + base + a * wld;
                }
                q[rr] = pk2(g01[0], g01[1]);
            }
            *(uint4*)&lds[d * 136 + w0] = make_uint4(q[0], q[1], q[2], q[3]);
        }
    }
    __syncthreads();
    f32x4 acc[2][4];
#pragma unroll
    for (int m = 0; m < 2; ++m)
#pragma unroll
        for (int n = 0; n < 4; ++n) acc[m][n] = (f32x4){0.f, 0.f, 0.f, 0.f};
    const bfu* Ab = acb + (size_t)b * N * N;
#pragma unroll
    for (int ks = 0; ks < 4; ++ks) {
        int k0 = ks * 32 + g4 * 8;
        bf16x8 bfr[4];
#pragma unroll
        for (int n = 0; n < 4; ++n)
            bfr[n] = *(const bf16x8*)&lds[(l16 + 16 * n) * 136 + k0];
#pragma unroll
        for (int m = 0; m < 2; ++m) {
            int i = wid * 32 + m * 16 + l16;
            bf16x8 afr = *(const bf16x8*)&Ab[(size_t)i * N + k0];
#pragma unroll
            for (int n = 0; n < 4; ++n)
                acc[m][n] = MFMA16(afr, bfr[n], acc[m][n], 0, 0, 0);
        }
    }
    __syncthreads();
#pragma unroll
    for (int m = 0; m < 2; ++m)
#pragma unroll
        for (int n = 0; n < 4; ++n)
#pragma unroll
            for (int r = 0; r < 4; ++r)
                lds[(wid * 32 + m * 16 + g4 * 4 + r) * 72 + l16 + 16 * n] = f2b(acc[m][n][r]);
    __syncthreads();
    {
        int i = t >> 1, half = t & 1;
        const uint4* src = (const uint4*)&lds[i * 72 + half * 32];
        uint4* dst = (uint4*)(T + (((size_t)bl * N + j) * N + i) * H + half * 32);
        dst[0] = src[0]; dst[1] = src[1]; dst[2] = src[2]; dst[3] = src[3];
    }
}

// ---------------- vectorized P-row build into LDS (bf16 U/V inputs)
__device__ __forceinline__ void build_P2(bfu* Pl, const bfu* U1b,
                                         const bfu* V1b, const bfu* arow,
                                         const bfu* Trow, const bfu* Tcol,
                                         const float* wl1, const float* bv1,
                                         int c, int t) {
    int wq = t >> 3, d0 = (t & 7) * 8;
    float wv[8], bvv[8], UcB[8], VcB[8];
    *(float4*)&wv[0]  = *(const float4*)(wl1 + d0);
    *(float4*)&wv[4]  = *(const float4*)(wl1 + d0 + 4);
    *(float4*)&bvv[0] = *(const float4*)(bv1 + d0);
    *(float4*)&bvv[4] = *(const float4*)(bv1 + d0 + 4);
    up8(*(const uint4*)&U1b[c * H + d0], UcB);
    up8(*(const uint4*)&V1b[c * H + d0], VcB);
#pragma unroll
    for (int e = 0; e < 8; ++e) { UcB[e] += bvv[e]; VcB[e] += bvv[e]; }
#pragma unroll
    for (int p = 0; p < 4; ++p) {
        int w = p * 32 + wq;
        float a = b2f(arow[w]);
        const bfu* rs = (w < c) ? U1b : V1b;
        float rv[8], tc[8], tw[8];
        up8(*(const uint4*)&rs[w * H + d0], rv);
        up8(*(const uint4*)&Trow[(size_t)w * H + d0], tc);
        up8(*(const uint4*)&Tcol[(size_t)w * N * H + d0], tw);
        unsigned q[4];
#pragma unroll
        for (int e = 0; e < 4; ++e) {
            float b0 = (w < c) ? VcB[2 * e] : UcB[2 * e];
            float b1 = (w < c) ? VcB[2 * e + 1] : UcB[2 * e + 1];
            float p0 = fmaxf(rv[2 * e]     + b0 + a * wv[2 * e]     + tc[2 * e]     + tw[2 * e],     0.f);
            float p1 = fmaxf(rv[2 * e + 1] + b1 + a * wv[2 * e + 1] + tc[2 * e + 1] + tw[2 * e + 1], 0.f);
            q[e] = pk2(p0, p1);
        }
        *(uint4*)&Pl[w * 72 + d0] = make_uint4(q[0], q[1], q[2], q[3]);
    }
}

// ---------------- t2 fused: P build; G2=P@W2+b2; S=P@W1+b1 (stored); T2=Ac@G2
__global__ __launch_bounds__(256) void t2_fused(const bfu* __restrict__ U1,
                                                const bfu* __restrict__ V1,
                                                const bfu* __restrict__ acb,
                                                const float* __restrict__ wl1,
                                                const float* __restrict__ bv1,
                                                const bfu* __restrict__ T1,
                                                const bfu* __restrict__ W2t,
                                                const float* __restrict__ bv2,
                                                const bfu* __restrict__ W1t,
                                                const float* __restrict__ bvS,
                                                bfu* __restrict__ Sout,
                                                bfu* __restrict__ T2, int b0) {
    int wid2 = xcd_swz(blockIdx.x, gridDim.x);
    int bl = wid2 >> 7, j = wid2 & 127;
    int b = b0 + bl;
    int t = threadIdx.x, lane = t & 63, wid = t >> 6;
    int l16 = lane & 15, g4 = lane >> 4;
    __shared__ bfu P[128 * 72];     // P rows -> S stage -> T2 stage
    __shared__ bfu Gt[64 * 136];    // G2 transposed [d=64][w=128], stride 136
    const bfu* T1b = T1 + (size_t)bl * N * N * H;
    build_P2(P, U1 + (size_t)b * N * H, V1 + (size_t)b * N * H,
             acb + ((size_t)b * N + j) * N,
             T1b + (size_t)j * N * H, T1b + (size_t)j * H,
             wl1, bv1, j, t);
    __syncthreads();
    // phase A: G2 = P@W2 + b2 (to Gt)  and  S = P@W1 + b1 (staged into P)
    f32x4 acc[2][4], sac[2][4];
#pragma unroll
    for (int m = 0; m < 2; ++m)
#pragma unroll
        for (int n = 0; n < 4; ++n) {
            acc[m][n] = (f32x4){0.f, 0.f, 0.f, 0.f};
            sac[m][n] = (f32x4){0.f, 0.f, 0.f, 0.f};
        }
#pragma unroll
    for (int ks = 0; ks < 2; ++ks) {
        int k0 = ks * 32 + g4 * 8;
        bf16x8 bw2[4], bw1[4];
#pragma unroll
        for (int n = 0; n < 4; ++n) {
            bw2[n] = *(const bf16x8*)&W2t[(l16 + 16 * n) * 64 + k0];
            bw1[n] = *(const bf16x8*)&W1t[(l16 + 16 * n) * 64 + k0];
        }
#pragma unroll
        for (int m = 0; m < 2; ++m) {
            bf16x8 afr = *(const bf16x8*)&P[(wid * 32 + m * 16 + l16) * 72 + k0];
#pragma unroll
            for (int n = 0; n < 4; ++n) {
                acc[m][n] = MFMA16(afr, bw2[n], acc[m][n], 0, 0, 0);
                sac[m][n] = MFMA16(afr, bw1[n], sac[m][n], 0, 0, 0);
            }
        }
    }
    {
        float bb2[4], bb1[4];
#pragma unroll
        for (int n = 0; n < 4; ++n) { bb2[n] = bv2[l16 + 16 * n]; bb1[n] = bvS[l16 + 16 * n]; }
#pragma unroll
        for (int m = 0; m < 2; ++m)
#pragma unroll
            for (int n = 0; n < 4; ++n) {
                uint2 q;
                q.x = pk2(acc[m][n][0] + bb2[n], acc[m][n][1] + bb2[n]);
                q.y = pk2(acc[m][n][2] + bb2[n], acc[m][n][3] + bb2[n]);
                *(uint2*)&Gt[(l16 + 16 * n) * 136 + wid * 32 + m * 16 + g4 * 4] = q;
                // stage S into own 32-row band of P (own-band reads already done)
#pragma unroll
                for (int r = 0; r < 4; ++r)
                    P[(wid * 32 + m * 16 + g4 * 4 + r) * 72 + l16 + 16 * n] =
                        f2b(sac[m][n][r] + bb1[n]);
            }
    }
    __syncthreads();
    // store S (all rows) + phase B: T2 = Ac @ G2
    {
        int i = t >> 1, half = t & 1;
        const uint4* src = (const uint4*)&P[i * 72 + half * 32];
        uint4* dst = (uint4*)(Sout + (((size_t)bl * N + j) * N + i) * H + half * 32);
        dst[0] = src[0]; dst[1] = src[1]; dst[2] = src[2]; dst[3] = src[3];
    }
#pragma unroll
    for (int m = 0; m < 2; ++m)
#pragma unroll
        for (int n = 0; n < 4; ++n) acc[m][n] = (f32x4){0.f, 0.f, 0.f, 0.f};
    const bfu* Ab = acb + (size_t)b * N * N;
#pragma unroll
    for (int ks = 0; ks < 4; ++ks) {
        int k0 = ks * 32 + g4 * 8;
        bf16x8 bfr[4];
#pragma unroll
        for (int n = 0; n < 4; ++n)
            bfr[n] = *(const bf16x8*)&Gt[(l16 + 16 * n) * 136 + k0];
#pragma unroll
        for (int m = 0; m < 2; ++m) {
            int i = wid * 32 + m * 16 + l16;
            bf16x8 afr = *(const bf16x8*)&Ab[(size_t)i * N + k0];
#pragma unroll
            for (int n = 0; n < 4; ++n)
                acc[m][n] = MFMA16(afr, bfr[n], acc[m][n], 0, 0, 0);
        }
    }
    __syncthreads();   // all waves' S-store LDS reads complete before T2 staging
#pragma unroll
    for (int m = 0; m < 2; ++m)
#pragma unroll
        for (int n = 0; n < 4; ++n)
#pragma unroll
            for (int r = 0; r < 4; ++r)
                P[(wid * 32 + m * 16 + g4 * 4 + r) * 72 + l16 + 16 * n] = f2b(acc[m][n][r]);
    __syncthreads();
    {
        int i = t >> 1, half = t & 1;
        const uint4* src = (const uint4*)&P[i * 72 + half * 32];
        uint4* dst = (uint4*)(T2 + (((size_t)bl * N + j) * N + i) * H + half * 32);
        dst[0] = src[0]; dst[1] = src[1]; dst[2] = src[2]; dst[3] = src[3];
    }
}

// ---------------- combine2 lite: part2[b,i,d] = sum_{j>i} relu(S[i,j,d]+T2[i,j,d]+T2[j,i,d])
__global__ __launch_bounds__(256) void combine2_lite(const bfu* __restrict__ S,
                                                     const bfu* __restrict__ T2,
                                                     float* __restrict__ part2, int b0) {
    int wid2 = xcd_swz(blockIdx.x, gridDim.x);
    int bl = wid2 >> 7, i = wid2 & 127;
    int b = b0 + bl;
    int t = threadIdx.x;
    __shared__ float red[32][64];
    int dc = t & 7, jg = t >> 3, d0 = dc * 8;
    const bfu* Srow  = S  + ((size_t)bl * N + i) * (size_t)(N * H);
    const bfu* T2row = T2 + ((size_t)bl * N + i) * (size_t)(N * H);
    const bfu* T2col = T2 + (size_t)bl * N * N * H + (size_t)i * H;
    float ps[8];
#pragma unroll
    for (int e = 0; e < 8; ++e) ps[e] = 0.f;
#pragma unroll
    for (int r = 0; r < 4; ++r) {
        int j = jg + r * 32;
        if (j > i) {
            float sv[8], ti[8], tj[8];
            up8(*(const uint4*)&Srow[(size_t)j * H + d0], sv);
            up8(*(const uint4*)&T2row[(size_t)j * H + d0], ti);
            up8(*(const uint4*)&T2col[(size_t)j * N * H + d0], tj);
#pragma unroll
            for (int e = 0; e < 8; ++e)
                ps[e] += fmaxf(sv[e] + ti[e] + tj[e], 0.f);
        }
    }
#pragma unroll
    for (int e = 0; e < 8; ++e) red[jg][d0 + e] = ps[e];
    __syncthreads();
    if (t < 64) {
        float s = 0.f;
#pragma unroll 8
        for (int g = 0; g < 32; ++g) s += red[g][t];
        part2[((size_t)b * N + i) * H + t] = s;
    }
}

// ---------------- fused tail: emb2 = rowsum(part2); out = concat(emb1,emb2)@cw + cb
__global__ __launch_bounds__(64) void tail_kernel(const float* __restrict__ part2,
                                                  const float* __restrict__ emb1,
                                                  const float* __restrict__ cw,
                                                  const float* __restrict__ cb,
                                                  float* __restrict__ out) {
    int b = blockIdx.x;
    int d = threadIdx.x;
    __shared__ float e2[64];
    float acc = 0.f;
#pragma unroll 8
    for (int n = 0; n < N; ++n) acc += part2[((size_t)b * N + n) * H + d];
    e2[d] = acc;
    __syncthreads();
    if (d < C) {
        float o = cb[d];
#pragma unroll 8
        for (int k = 0; k < H; ++k) {
            o += emb1[(size_t)b * H + k] * cw[(size_t)k * C + d];
            o += e2[k] * cw[(size_t)(H + k) * C + d];
        }
        out[(size_t)b * C + d] = o;
    }
}

extern "C" void kernel_launch(void* const* d_in, const int* in_sizes, int n_in,
                              void* d_out, int out_size, void* d_ws, size_t ws_size,
                              hipStream_t stream) {
    const float* x    = (const float*)d_in[0];
    const float* adj  = (const float*)d_in[1];
    const float* w11  = (const float*)d_in[2];
    const float* b11  = (const float*)d_in[3];
    const float* w12  = (const float*)d_in[4];
    const float* b12  = (const float*)d_in[5];
    const float* w21  = (const float*)d_in[6];
    const float* b21  = (const float*)d_in[7];
    const float* w22  = (const float*)d_in[8];
    const float* b22  = (const float*)d_in[9];
    const float* p1w1 = (const float*)d_in[10];
    const float* p1b1 = (const float*)d_in[11];
    const float* p1w2 = (const float*)d_in[12];
    const float* p1b2 = (const float*)d_in[13];
    const float* p2w1 = (const float*)d_in[14];
    const float* p2b1 = (const float*)d_in[15];
    const float* p2w2 = (const float*)d_in[16];
    const float* p2b2 = (const float*)d_in[17];
    const float* cw   = (const float*)d_in[18];
    const float* cb   = (const float*)d_in[19];
    float* out = (float*)d_out;

    const size_t NBH = (size_t)B * N * H;            // 262144
    const size_t BIG = (size_t)N * N * H;            // 1,048,576

    float* part2 = (float*)d_ws;                     // NBH
    float* emb1  = part2 + NBH;                      // B*H
    float* emb2  = emb1 + (size_t)B * H;             // B*H (layout slot)
    bfu* U1   = (bfu*)(emb2 + (size_t)B * H);        // NBH each
    bfu* V1   = U1 + NBH;
    bfu* U2   = V1 + NBH;
    bfu* V2   = U2 + NBH;
    bfu* acb  = V2 + NBH;                            // B*N*N
    bfu* adjf = acb + (size_t)B * N * N;             // B*N*N
    bfu* w11t = adjf + (size_t)B * N * N;
    bfu* w12t = w11t + 32 * 64;
    bfu* w21t = w12t + 32 * 64;
    bfu* w22t = w21t + 64 * 64;
    bfu* u1t  = w22t + 64 * 64;
    bfu* v1t  = u1t + 64 * 64;
    bfu* u2t  = v1t + 64 * 64;
    bfu* v2t  = u2t + 64 * 64;
    bfu* W1t  = v2t + 64 * 64;
    bfu* W2t  = W1t + 64 * 64;
    bfu* bigBase = W2t + 64 * 64;
    size_t smallBytes = (char*)bigBase - (char*)d_ws;

    // three big buffers: T1, T2, S
    int CB = B;
    while (CB > 1 && smallBytes + 3ull * CB * BIG * sizeof(bfu) > ws_size) CB >>= 1;
    bfu* T1 = bigBase;
    bfu* T2 = T1 + (size_t)CB * BIG;
    bfu* Sb = T2 + (size_t)CB * BIG;

    // fused prep (512 adj blocks + 10 weight blocks)
    {
        WT p;
        const float* srcs[10] = {w11, w12, w21, w22,
                                 p1w1, p1w1 + 64 * H, p1w2, p1w2 + 64 * H,
                                 p2w1, p2w2};
        bfu* dsts[10] = {w11t, w12t, w21t, w22t, u1t, v1t, u2t, v2t, W1t, W2t};
        int Ks[10] = {32, 32, 64, 64, 64, 64, 64, 64, 64, 64};
        for (int q = 0; q < 10; ++q) { p.src[q] = srcs[q]; p.dst[q] = dsts[q]; p.K[q] = Ks[q]; }
        prep_all<<<dim3(512 + 10), 256, 0, stream>>>(adj, acb, adjf, p);
    }
    // fused front-end
    gnn_front<<<dim3(B), 256, 0, stream>>>(x, adjf, w11t, b11, w12t, b12,
                                           w21t, b21, w22t, b22,
                                           u1t, v1t, u2t, v2t,
                                           U1, V1, U2, V2, emb1);
    // pair stages
    for (int b0 = 0; b0 < B; b0 += CB) {
        dim3 cg(CB * N);
        t1_mfma<<<cg, 256, 0, stream>>>(U2, V2, acb, p1w2 + 128 * H, p1b2, T1, b0);
        t2_fused<<<cg, 256, 0, stream>>>(U1, V1, acb, p1w1 + 128 * H, p1b1,
                                         T1, W2t, p2b2, W1t, p2b1, Sb, T2, b0);
        combine2_lite<<<cg, 256, 0, stream>>>(Sb, T2, part2, b0);
    }
    // fused tail
    tail_kernel<<<dim3(B), 64, 0, stream>>>(part2, emb1, cw, cb, out);
}

// Round 14
// 162.525 us; speedup vs baseline: 1.1326x; 1.1326x over previous
//
#include <hip/hip_runtime.h>

#define B 32
#define N 128
#define DD 32
#define H 64
#define C 10

typedef unsigned short bfu;   // raw bf16 storage
typedef __attribute__((ext_vector_type(8))) short bf16x8;  // 8 bf16 (4 VGPRs)
typedef __attribute__((ext_vector_type(4))) float f32x4;   // MFMA accumulator

#define MFMA16 __builtin_amdgcn_mfma_f32_16x16x32_bf16

__device__ __forceinline__ float b2f(bfu v) {
    union { unsigned u; float f; } x; x.u = ((unsigned)v) << 16; return x.f;
}
__device__ __forceinline__ bfu f2b(float f) {
    union { __bf16 b; bfu u; } c; c.b = (__bf16)f; return c.u;
}
__device__ __forceinline__ float lo2f(unsigned u) {
    union { unsigned x; float f; } c; c.x = u << 16; return c.f;
}
__device__ __forceinline__ float hi2f(unsigned u) {
    union { unsigned x; float f; } c; c.x = u & 0xffff0000u; return c.f;
}
__device__ __forceinline__ void up8(uint4 u, float* f) {
    f[0] = lo2f(u.x); f[1] = hi2f(u.x); f[2] = lo2f(u.y); f[3] = hi2f(u.y);
    f[4] = lo2f(u.z); f[5] = hi2f(u.z); f[6] = lo2f(u.w); f[7] = hi2f(u.w);
}
__device__ __forceinline__ unsigned pk2(float a, float b) {
    return (unsigned)f2b(a) | ((unsigned)f2b(b) << 16);
}

// ---------------- fused prep: blocks [0,512) convert adj; [512,522) transpose weights
struct WT { const float* src[10]; bfu* dst[10]; int K[10]; };
__global__ __launch_bounds__(256) void prep_all(const float* __restrict__ adj,
                                                bfu* __restrict__ acb,
                                                bfu* __restrict__ adjf, WT p) {
    int blk = blockIdx.x;
    if (blk < 512) {
        int idx = blk * 256 + threadIdx.x;
        float4 v = ((const float4*)adj)[idx];
        int e0 = idx * 4;
        int w = e0 & 127;
        int i = (e0 >> 7) & 127;
        ushort4 o;
        o.x = f2b((i == w    ) ? 0.f : v.x);
        o.y = f2b((i == w + 1) ? 0.f : v.y);
        o.z = f2b((i == w + 2) ? 0.f : v.z);
        o.w = f2b((i == w + 3) ? 0.f : v.w);
        ((ushort4*)acb)[idx] = o;
        ushort4 oF;
        oF.x = f2b(v.x); oF.y = f2b(v.y); oF.z = f2b(v.z); oF.w = f2b(v.w);
        ((ushort4*)adjf)[idx] = oF;
    } else {
        int m = blk - 512;
        const float* S = p.src[m];
        bfu* D = p.dst[m];
        int K = p.K[m];
        int t = threadIdx.x; int d = t & 63;
        for (int k = t >> 6; k < K; k += 4)
            D[d * K + k] = f2b(S[k * 64 + d]);
    }
}

// ---------------- fused front-end: per-batch GNN layers + emb1 + h2 out (bf16)
__global__ __launch_bounds__(256) void gnn_front(const float* __restrict__ x,
                                                 const bfu* __restrict__ adjf,
                                                 const bfu* __restrict__ w11t,
                                                 const float* __restrict__ b11,
                                                 const bfu* __restrict__ w12t,
                                                 const float* __restrict__ b12,
                                                 const bfu* __restrict__ w21t,
                                                 const float* __restrict__ b21,
                                                 const bfu* __restrict__ w22t,
                                                 const float* __restrict__ b22,
                                                 bfu* __restrict__ h2g,
                                                 float* __restrict__ emb1) {
    int b = blockIdx.x;
    int t = threadIdx.x, lane = t & 63, wid = t >> 6;
    int l16 = lane & 15, g4 = lane >> 4;
    __shared__ bfu Af[128 * 136];
    __shared__ bfu Yt[64 * 136];
    __shared__ bfu Hs[128 * 72];
    __shared__ bfu Xs[128 * 40];
    __shared__ float red[16][64];
    {
        int i = t >> 1, half = t & 1;
        const uint4* src = (const uint4*)(adjf + ((size_t)b * N + i) * N + half * 64);
        uint4* dst = (uint4*)&Af[i * 136 + half * 64];
#pragma unroll
        for (int q = 0; q < 8; ++q) dst[q] = src[q];
        const float4* sx = (const float4*)(x + ((size_t)b * N + i) * DD + half * 16);
        float xv[16];
        *(float4*)&xv[0]  = sx[0]; *(float4*)&xv[4]  = sx[1];
        *(float4*)&xv[8]  = sx[2]; *(float4*)&xv[12] = sx[3];
        unsigned q[8];
#pragma unroll
        for (int e = 0; e < 8; ++e) q[e] = pk2(xv[2 * e], xv[2 * e + 1]);
        uint4* dx = (uint4*)&Xs[i * 40 + half * 16];
        dx[0] = make_uint4(q[0], q[1], q[2], q[3]);
        dx[1] = make_uint4(q[4], q[5], q[6], q[7]);
    }
    __syncthreads();
    f32x4 a1[2][4], a2[2][4];
#define ZERO(A) _Pragma("unroll") for (int m = 0; m < 2; ++m) _Pragma("unroll") for (int n = 0; n < 4; ++n) A[m][n] = (f32x4){0.f,0.f,0.f,0.f};
    ZERO(a1); ZERO(a2);
    {
        int k0 = g4 * 8;
        bf16x8 bw1[4], bw2[4];
#pragma unroll
        for (int n = 0; n < 4; ++n) {
            bw1[n] = *(const bf16x8*)&w11t[(l16 + 16 * n) * 32 + k0];
            bw2[n] = *(const bf16x8*)&w12t[(l16 + 16 * n) * 32 + k0];
        }
#pragma unroll
        for (int m = 0; m < 2; ++m) {
            bf16x8 afr = *(const bf16x8*)&Xs[(wid * 32 + m * 16 + l16) * 40 + k0];
#pragma unroll
            for (int n = 0; n < 4; ++n) {
                a1[m][n] = MFMA16(afr, bw1[n], a1[m][n], 0, 0, 0);
                a2[m][n] = MFMA16(afr, bw2[n], a2[m][n], 0, 0, 0);
            }
        }
    }
    {
        float bb[4];
#pragma unroll
        for (int n = 0; n < 4; ++n) bb[n] = b12[l16 + 16 * n];
#pragma unroll
        for (int m = 0; m < 2; ++m)
#pragma unroll
            for (int n = 0; n < 4; ++n) {
                uint2 q;
                q.x = pk2(a2[m][n][0] + bb[n], a2[m][n][1] + bb[n]);
                q.y = pk2(a2[m][n][2] + bb[n], a2[m][n][3] + bb[n]);
                *(uint2*)&Yt[(l16 + 16 * n) * 136 + wid * 32 + m * 16 + g4 * 4] = q;
            }
    }
    __syncthreads();
    ZERO(a2);
#pragma unroll
    for (int ks = 0; ks < 4; ++ks) {
        int k0 = ks * 32 + g4 * 8;
        bf16x8 bfr[4];
#pragma unroll
        for (int n = 0; n < 4; ++n) bfr[n] = *(const bf16x8*)&Yt[(l16 + 16 * n) * 136 + k0];
#pragma unroll
        for (int m = 0; m < 2; ++m) {
            bf16x8 afr = *(const bf16x8*)&Af[(wid * 32 + m * 16 + l16) * 136 + k0];
#pragma unroll
            for (int n = 0; n < 4; ++n) a2[m][n] = MFMA16(afr, bfr[n], a2[m][n], 0, 0, 0);
        }
    }
    {
        float bb[4];
#pragma unroll
        for (int n = 0; n < 4; ++n) bb[n] = b11[l16 + 16 * n];
#pragma unroll
        for (int m = 0; m < 2; ++m)
#pragma unroll
            for (int n = 0; n < 4; ++n)
#pragma unroll
                for (int r = 0; r < 4; ++r)
                    Hs[(wid * 32 + m * 16 + g4 * 4 + r) * 72 + l16 + 16 * n] =
                        f2b(fmaxf(a1[m][n][r] + bb[n] + a2[m][n][r], 0.f));
    }
    __syncthreads();
    ZERO(a1); ZERO(a2);
#pragma unroll
    for (int ks = 0; ks < 2; ++ks) {
        int k0 = ks * 32 + g4 * 8;
        bf16x8 bw1[4], bw2[4];
#pragma unroll
        for (int n = 0; n < 4; ++n) {
            bw1[n] = *(const bf16x8*)&w21t[(l16 + 16 * n) * 64 + k0];
            bw2[n] = *(const bf16x8*)&w22t[(l16 + 16 * n) * 64 + k0];
        }
#pragma unroll
        for (int m = 0; m < 2; ++m) {
            bf16x8 afr = *(const bf16x8*)&Hs[(wid * 32 + m * 16 + l16) * 72 + k0];
#pragma unroll
            for (int n = 0; n < 4; ++n) {
                a1[m][n] = MFMA16(afr, bw1[n], a1[m][n], 0, 0, 0);
                a2[m][n] = MFMA16(afr, bw2[n], a2[m][n], 0, 0, 0);
            }
        }
    }
    {
        float bb[4];
#pragma unroll
        for (int n = 0; n < 4; ++n) bb[n] = b22[l16 + 16 * n];
#pragma unroll
        for (int m = 0; m < 2; ++m)
#pragma unroll
            for (int n = 0; n < 4; ++n) {
                uint2 q;
                q.x = pk2(a2[m][n][0] + bb[n], a2[m][n][1] + bb[n]);
                q.y = pk2(a2[m][n][2] + bb[n], a2[m][n][3] + bb[n]);
                *(uint2*)&Yt[(l16 + 16 * n) * 136 + wid * 32 + m * 16 + g4 * 4] = q;
            }
    }
    __syncthreads();
    ZERO(a2);
#pragma unroll
    for (int ks = 0; ks < 4; ++ks) {
        int k0 = ks * 32 + g4 * 8;
        bf16x8 bfr[4];
#pragma unroll
        for (int n = 0; n < 4; ++n) bfr[n] = *(const bf16x8*)&Yt[(l16 + 16 * n) * 136 + k0];
#pragma unroll
        for (int m = 0; m < 2; ++m) {
            bf16x8 afr = *(const bf16x8*)&Af[(wid * 32 + m * 16 + l16) * 136 + k0];
#pragma unroll
            for (int n = 0; n < 4; ++n) a2[m][n] = MFMA16(afr, bfr[n], a2[m][n], 0, 0, 0);
        }
    }
    {
        float bb[4], s[4] = {0.f, 0.f, 0.f, 0.f};
#pragma unroll
        for (int n = 0; n < 4; ++n) bb[n] = b21[l16 + 16 * n];
#pragma unroll
        for (int m = 0; m < 2; ++m)
#pragma unroll
            for (int n = 0; n < 4; ++n)
#pragma unroll
                for (int r = 0; r < 4; ++r) {
                    float v = fmaxf(a1[m][n][r] + bb[n] + a2[m][n][r], 0.f);
                    Hs[(wid * 32 + m * 16 + g4 * 4 + r) * 72 + l16 + 16 * n] = f2b(v);
                    s[n] += v;
                }
#pragma unroll
        for (int n = 0; n < 4; ++n) red[wid * 4 + g4][l16 + 16 * n] = s[n];
    }
    __syncthreads();
    if (t < 64) {
        float e = 0.f;
#pragma unroll
        for (int q = 0; q < 16; ++q) e += red[q][t];
        emb1[b * 64 + t] = e;
    }
    // write h2 (bf16) coalesced for uv_proj
    {
        int i = t >> 1, half = t & 1;
        const uint4* src = (const uint4*)&Hs[i * 72 + half * 32];
        uint4* dst = (uint4*)(h2g + ((size_t)b * N + i) * H + half * 32);
        dst[0] = src[0]; dst[1] = src[1]; dst[2] = src[2]; dst[3] = src[3];
    }
#undef ZERO
}

// ---------------- U/V projections: one block per (batch, projection)
__global__ __launch_bounds__(256) void uv_proj(const bfu* __restrict__ h2g,
                                               const bfu* __restrict__ u1t,
                                               const bfu* __restrict__ v1t,
                                               const bfu* __restrict__ u2t,
                                               const bfu* __restrict__ v2t,
                                               bfu* __restrict__ U1,
                                               bfu* __restrict__ V1,
                                               bfu* __restrict__ U2,
                                               bfu* __restrict__ V2) {
    int blk = blockIdx.x;
    int b = blk >> 2, o = blk & 3;
    const bfu* wts[4] = {u1t, v1t, u2t, v2t};
    bfu* outs[4] = {U1, V1, U2, V2};
    const bfu* wt = wts[o];
    bfu* outp = outs[o];
    int t = threadIdx.x, lane = t & 63, wid = t >> 6;
    int l16 = lane & 15, g4 = lane >> 4;
    __shared__ bfu Hs[128 * 72];
    {
        int i = t >> 1, half = t & 1;
        const uint4* src = (const uint4*)(h2g + ((size_t)b * N + i) * H + half * 32);
        uint4* dst = (uint4*)&Hs[i * 72 + half * 32];
        dst[0] = src[0]; dst[1] = src[1]; dst[2] = src[2]; dst[3] = src[3];
    }
    __syncthreads();
    f32x4 a1[2][4];
#pragma unroll
    for (int m = 0; m < 2; ++m)
#pragma unroll
        for (int n = 0; n < 4; ++n) a1[m][n] = (f32x4){0.f, 0.f, 0.f, 0.f};
#pragma unroll
    for (int ks = 0; ks < 2; ++ks) {
        int k0 = ks * 32 + g4 * 8;
        bf16x8 bw[4];
#pragma unroll
        for (int n = 0; n < 4; ++n)
            bw[n] = *(const bf16x8*)&wt[(l16 + 16 * n) * 64 + k0];
#pragma unroll
        for (int m = 0; m < 2; ++m) {
            bf16x8 afr = *(const bf16x8*)&Hs[(wid * 32 + m * 16 + l16) * 72 + k0];
#pragma unroll
            for (int n = 0; n < 4; ++n) a1[m][n] = MFMA16(afr, bw[n], a1[m][n], 0, 0, 0);
        }
    }
    // stage into own 32-row band (own-band A reads complete in program order)
#pragma unroll
    for (int m = 0; m < 2; ++m)
#pragma unroll
        for (int n = 0; n < 4; ++n)
#pragma unroll
            for (int r = 0; r < 4; ++r)
                Hs[(wid * 32 + m * 16 + g4 * 4 + r) * 72 + l16 + 16 * n] = f2b(a1[m][n][r]);
    __syncthreads();
    {
        int i = t >> 1, half = t & 1;
        const uint4* src = (const uint4*)&Hs[i * 72 + half * 32];
        uint4* dst = (uint4*)(outp + ((size_t)b * N + i) * H + half * 32);
        dst[0] = src[0]; dst[1] = src[1]; dst[2] = src[2]; dst[3] = src[3];
    }
}

// ---------------- XCD-aware bijective swizzle (grid divisible by 8)
__device__ __forceinline__ int xcd_swz(int wg, int nwg) {
    return (wg & 7) * (nwg >> 3) + (wg >> 3);
}

// ---------------- t1: T1[bl,j,i,d] = sum_w ac[b,i,w]*G[j,w,d]  via MFMA
__global__ __launch_bounds__(256) void t1_mfma(const bfu* __restrict__ U2,
                                               const bfu* __restrict__ V2,
                                               const bfu* __restrict__ acb,
                                               const float* __restrict__ wl,
                                               const float* __restrict__ bv,
                                               bfu* __restrict__ T, int b0) {
    int wid2 = xcd_swz(blockIdx.x, gridDim.x);
    int bl = wid2 >> 7, j = wid2 & 127;
    int b = b0 + bl;
    int t = threadIdx.x, lane = t & 63, wid = t >> 6;
    int l16 = lane & 15, g4 = lane >> 4;
    __shared__ bfu lds[128 * 72];
    __shared__ float arl[N];
    const bfu* arow = acb + ((size_t)b * N + j) * N;
    if (t < N) arl[t] = b2f(arow[t]);
    __syncthreads();
    {
        int d = lane;
        const bfu* U2b = U2 + (size_t)b * N * H;
        const bfu* V2b = V2 + (size_t)b * N * H;
        float wld = wl[d], bvd = bv[d];
        float UjB = b2f(U2b[j * H + d]) + bvd, VjB = b2f(V2b[j * H + d]) + bvd;
#pragma unroll
        for (int p = 0; p < 4; ++p) {
            int w0 = p * 32 + wid * 8;
            unsigned q[4];
#pragma unroll
            for (int rr = 0; rr < 4; ++rr) {
                float g01[2];
#pragma unroll
                for (int hh = 0; hh < 2; ++hh) {
                    int w = w0 + rr * 2 + hh;
                    float a = arl[w];
                    float rvar = (w < j) ? b2f(U2b[w * H + d]) : b2f(V2b[w * H + d]);
                    float base = (w < j) ? VjB : UjB;
                    g01[hh] = rvar + base + a * wld;
                }
                q[rr] = pk2(g01[0], g01[1]);
            }
            *(uint4*)&lds[d * 136 + w0] = make_uint4(q[0], q[1], q[2], q[3]);
        }
    }
    __syncthreads();
    f32x4 acc[2][4];
#pragma unroll
    for (int m = 0; m < 2; ++m)
#pragma unroll
        for (int n = 0; n < 4; ++n) acc[m][n] = (f32x4){0.f, 0.f, 0.f, 0.f};
    const bfu* Ab = acb + (size_t)b * N * N;
#pragma unroll
    for (int ks = 0; ks < 4; ++ks) {
        int k0 = ks * 32 + g4 * 8;
        bf16x8 bfr[4];
#pragma unroll
        for (int n = 0; n < 4; ++n)
            bfr[n] = *(const bf16x8*)&lds[(l16 + 16 * n) * 136 + k0];
#pragma unroll
        for (int m = 0; m < 2; ++m) {
            int i = wid * 32 + m * 16 + l16;
            bf16x8 afr = *(const bf16x8*)&Ab[(size_t)i * N + k0];
#pragma unroll
            for (int n = 0; n < 4; ++n)
                acc[m][n] = MFMA16(afr, bfr[n], acc[m][n], 0, 0, 0);
        }
    }
    __syncthreads();
#pragma unroll
    for (int m = 0; m < 2; ++m)
#pragma unroll
        for (int n = 0; n < 4; ++n)
#pragma unroll
            for (int r = 0; r < 4; ++r)
                lds[(wid * 32 + m * 16 + g4 * 4 + r) * 72 + l16 + 16 * n] = f2b(acc[m][n][r]);
    __syncthreads();
    {
        int i = t >> 1, half = t & 1;
        const uint4* src = (const uint4*)&lds[i * 72 + half * 32];
        uint4* dst = (uint4*)(T + (((size_t)bl * N + j) * N + i) * H + half * 32);
        dst[0] = src[0]; dst[1] = src[1]; dst[2] = src[2]; dst[3] = src[3];
    }
}

// ---------------- vectorized P-row build into LDS (bf16 U/V inputs)
__device__ __forceinline__ void build_P2(bfu* Pl, const bfu* U1b,
                                         const bfu* V1b, const bfu* arow,
                                         const bfu* Trow, const bfu* Tcol,
                                         const float* wl1, const float* bv1,
                                         int c, int t) {
    int wq = t >> 3, d0 = (t & 7) * 8;
    float wv[8], bvv[8], UcB[8], VcB[8];
    *(float4*)&wv[0]  = *(const float4*)(wl1 + d0);
    *(float4*)&wv[4]  = *(const float4*)(wl1 + d0 + 4);
    *(float4*)&bvv[0] = *(const float4*)(bv1 + d0);
    *(float4*)&bvv[4] = *(const float4*)(bv1 + d0 + 4);
    up8(*(const uint4*)&U1b[c * H + d0], UcB);
    up8(*(const uint4*)&V1b[c * H + d0], VcB);
#pragma unroll
    for (int e = 0; e < 8; ++e) { UcB[e] += bvv[e]; VcB[e] += bvv[e]; }
#pragma unroll
    for (int p = 0; p < 4; ++p) {
        int w = p * 32 + wq;
        float a = b2f(arow[w]);
        const bfu* rs = (w < c) ? U1b : V1b;
        float rv[8], tc[8], tw[8];
        up8(*(const uint4*)&rs[w * H + d0], rv);
        up8(*(const uint4*)&Trow[(size_t)w * H + d0], tc);
        up8(*(const uint4*)&Tcol[(size_t)w * N * H + d0], tw);
        unsigned q[4];
#pragma unroll
        for (int e = 0; e < 4; ++e) {
            float b0 = (w < c) ? VcB[2 * e] : UcB[2 * e];
            float b1 = (w < c) ? VcB[2 * e + 1] : UcB[2 * e + 1];
            float p0 = fmaxf(rv[2 * e]     + b0 + a * wv[2 * e]     + tc[2 * e]     + tw[2 * e],     0.f);
            float p1 = fmaxf(rv[2 * e + 1] + b1 + a * wv[2 * e + 1] + tc[2 * e + 1] + tw[2 * e + 1], 0.f);
            q[e] = pk2(p0, p1);
        }
        *(uint4*)&Pl[w * 72 + d0] = make_uint4(q[0], q[1], q[2], q[3]);
    }
}

// ---------------- t2 fused (R11 form): P build; G2 = P@W2 + b2; T2 = Ac@G2
__global__ __launch_bounds__(256) void t2_fused(const bfu* __restrict__ U1,
                                                const bfu* __restrict__ V1,
                                                const bfu* __restrict__ acb,
                                                const float* __restrict__ wl1,
                                                const float* __restrict__ bv1,
                                                const bfu* __restrict__ T1,
                                                const bfu* __restrict__ W2t,
                                                const float* __restrict__ bv2,
                                                bfu* __restrict__ T2, int b0) {
    int wid2 = xcd_swz(blockIdx.x, gridDim.x);
    int bl = wid2 >> 7, j = wid2 & 127;
    int b = b0 + bl;
    int t = threadIdx.x, lane = t & 63, wid = t >> 6;
    int l16 = lane & 15, g4 = lane >> 4;
    __shared__ bfu P[128 * 72];
    __shared__ bfu Gt[64 * 136];
    const bfu* T1b = T1 + (size_t)bl * N * N * H;
    build_P2(P, U1 + (size_t)b * N * H, V1 + (size_t)b * N * H,
             acb + ((size_t)b * N + j) * N,
             T1b + (size_t)j * N * H, T1b + (size_t)j * H,
             wl1, bv1, j, t);
    __syncthreads();
    f32x4 acc[2][4];
#pragma unroll
    for (int m = 0; m < 2; ++m)
#pragma unroll
        for (int n = 0; n < 4; ++n) acc[m][n] = (f32x4){0.f, 0.f, 0.f, 0.f};
#pragma unroll
    for (int ks = 0; ks < 2; ++ks) {
        int k0 = ks * 32 + g4 * 8;
        bf16x8 bw[4];
#pragma unroll
        for (int n = 0; n < 4; ++n)
            bw[n] = *(const bf16x8*)&W2t[(l16 + 16 * n) * 64 + k0];
#pragma unroll
        for (int m = 0; m < 2; ++m) {
            bf16x8 afr = *(const bf16x8*)&P[(wid * 32 + m * 16 + l16) * 72 + k0];
#pragma unroll
            for (int n = 0; n < 4; ++n)
                acc[m][n] = MFMA16(afr, bw[n], acc[m][n], 0, 0, 0);
        }
    }
    {
        float bb[4];
#pragma unroll
        for (int n = 0; n < 4; ++n) bb[n] = bv2[l16 + 16 * n];
#pragma unroll
        for (int m = 0; m < 2; ++m)
#pragma unroll
            for (int n = 0; n < 4; ++n) {
                uint2 q;
                q.x = pk2(acc[m][n][0] + bb[n], acc[m][n][1] + bb[n]);
                q.y = pk2(acc[m][n][2] + bb[n], acc[m][n][3] + bb[n]);
                *(uint2*)&Gt[(l16 + 16 * n) * 136 + wid * 32 + m * 16 + g4 * 4] = q;
            }
    }
    __syncthreads();
#pragma unroll
    for (int m = 0; m < 2; ++m)
#pragma unroll
        for (int n = 0; n < 4; ++n) acc[m][n] = (f32x4){0.f, 0.f, 0.f, 0.f};
    const bfu* Ab = acb + (size_t)b * N * N;
#pragma unroll
    for (int ks = 0; ks < 4; ++ks) {
        int k0 = ks * 32 + g4 * 8;
        bf16x8 bfr[4];
#pragma unroll
        for (int n = 0; n < 4; ++n)
            bfr[n] = *(const bf16x8*)&Gt[(l16 + 16 * n) * 136 + k0];
#pragma unroll
        for (int m = 0; m < 2; ++m) {
            int i = wid * 32 + m * 16 + l16;
            bf16x8 afr = *(const bf16x8*)&Ab[(size_t)i * N + k0];
#pragma unroll
            for (int n = 0; n < 4; ++n)
                acc[m][n] = MFMA16(afr, bfr[n], acc[m][n], 0, 0, 0);
        }
    }
#pragma unroll
    for (int m = 0; m < 2; ++m)
#pragma unroll
        for (int n = 0; n < 4; ++n)
#pragma unroll
            for (int r = 0; r < 4; ++r)
                P[(wid * 32 + m * 16 + g4 * 4 + r) * 72 + l16 + 16 * n] = f2b(acc[m][n][r]);
    __syncthreads();
    {
        int i = t >> 1, half = t & 1;
        const uint4* src = (const uint4*)&P[i * 72 + half * 32];
        uint4* dst = (uint4*)(T2 + (((size_t)bl * N + j) * N + i) * H + half * 32);
        dst[0] = src[0]; dst[1] = src[1]; dst[2] = src[2]; dst[3] = src[3];
    }
}

// ---------------- combine2 fused (R11 form)
__global__ __launch_bounds__(256) void combine2_fused(const bfu* __restrict__ U1,
                                                      const bfu* __restrict__ V1,
                                                      const bfu* __restrict__ acb,
                                                      const float* __restrict__ wl1,
                                                      const float* __restrict__ bv1,
                                                      const bfu* __restrict__ T1,
                                                      const bfu* __restrict__ W1t,
                                                      const float* __restrict__ bv2,
                                                      const bfu* __restrict__ T2,
                                                      float* __restrict__ part2, int b0) {
    int wid2 = xcd_swz(blockIdx.x, gridDim.x);
    int bl = wid2 >> 7, i = wid2 & 127;
    int b = b0 + bl;
    int t = threadIdx.x, lane = t & 63, wid = t >> 6;
    int l16 = lane & 15, g4 = lane >> 4;
    __shared__ bfu P[128 * 72];
    __shared__ float red[32][64];
    const bfu* T1b = T1 + (size_t)bl * N * N * H;
    build_P2(P, U1 + (size_t)b * N * H, V1 + (size_t)b * N * H,
             acb + ((size_t)b * N + i) * N,
             T1b + (size_t)i * N * H, T1b + (size_t)i * H,
             wl1, bv1, i, t);
    __syncthreads();
    f32x4 acc[2][4];
#pragma unroll
    for (int m = 0; m < 2; ++m)
#pragma unroll
        for (int n = 0; n < 4; ++n) acc[m][n] = (f32x4){0.f, 0.f, 0.f, 0.f};
#pragma unroll
    for (int ks = 0; ks < 2; ++ks) {
        int k0 = ks * 32 + g4 * 8;
        bf16x8 bw[4];
#pragma unroll
        for (int n = 0; n < 4; ++n)
            bw[n] = *(const bf16x8*)&W1t[(l16 + 16 * n) * 64 + k0];
#pragma unroll
        for (int m = 0; m < 2; ++m) {
            bf16x8 afr = *(const bf16x8*)&P[(wid * 32 + m * 16 + l16) * 72 + k0];
#pragma unroll
            for (int n = 0; n < 4; ++n)
                acc[m][n] = MFMA16(afr, bw[n], acc[m][n], 0, 0, 0);
        }
    }
    {
        float bb[4];
#pragma unroll
        for (int n = 0; n < 4; ++n) bb[n] = bv2[l16 + 16 * n];
#pragma unroll
        for (int m = 0; m < 2; ++m)
#pragma unroll
            for (int n = 0; n < 4; ++n)
#pragma unroll
                for (int r = 0; r < 4; ++r)
                    P[(wid * 32 + m * 16 + g4 * 4 + r) * 72 + l16 + 16 * n] =
                        f2b(acc[m][n][r] + bb[n]);
    }
    __syncthreads();
    int dc = t & 7, jg = t >> 3, d0 = dc * 8;
    float ps[8];
#pragma unroll
    for (int e = 0; e < 8; ++e) ps[e] = 0.f;
    const bfu* T2b = T2 + (size_t)bl * N * N * H;
#pragma unroll
    for (int r = 0; r < 4; ++r) {
        int j = jg + r * 32;
        if (j > i) {
            float ti[8], tj[8], sv[8];
            up8(*(const uint4*)&T2b[((size_t)i * N + j) * H + d0], ti);
            up8(*(const uint4*)&T2b[((size_t)j * N + i) * H + d0], tj);
            up8(*(const uint4*)&P[j * 72 + d0], sv);
#pragma unroll
            for (int e = 0; e < 8; ++e)
                ps[e] += fmaxf(sv[e] + ti[e] + tj[e], 0.f);
        }
    }
#pragma unroll
    for (int e = 0; e < 8; ++e) red[jg][d0 + e] = ps[e];
    __syncthreads();
    if (t < 64) {
        float s = 0.f;
#pragma unroll 8
        for (int g = 0; g < 32; ++g) s += red[g][t];
        part2[((size_t)b * N + i) * H + t] = s;
    }
}

// ---------------- fused tail: emb2 = rowsum(part2); out = concat(emb1,emb2)@cw + cb
__global__ __launch_bounds__(64) void tail_kernel(const float* __restrict__ part2,
                                                  const float* __restrict__ emb1,
                                                  const float* __restrict__ cw,
                                                  const float* __restrict__ cb,
                                                  float* __restrict__ out) {
    int b = blockIdx.x;
    int d = threadIdx.x;
    __shared__ float e2[64];
    float acc = 0.f;
#pragma unroll 8
    for (int n = 0; n < N; ++n) acc += part2[((size_t)b * N + n) * H + d];
    e2[d] = acc;
    __syncthreads();
    if (d < C) {
        float o = cb[d];
#pragma unroll 8
        for (int k = 0; k < H; ++k) {
            o += emb1[(size_t)b * H + k] * cw[(size_t)k * C + d];
            o += e2[k] * cw[(size_t)(H + k) * C + d];
        }
        out[(size_t)b * C + d] = o;
    }
}

extern "C" void kernel_launch(void* const* d_in, const int* in_sizes, int n_in,
                              void* d_out, int out_size, void* d_ws, size_t ws_size,
                              hipStream_t stream) {
    const float* x    = (const float*)d_in[0];
    const float* adj  = (const float*)d_in[1];
    const float* w11  = (const float*)d_in[2];
    const float* b11  = (const float*)d_in[3];
    const float* w12  = (const float*)d_in[4];
    const float* b12  = (const float*)d_in[5];
    const float* w21  = (const float*)d_in[6];
    const float* b21  = (const float*)d_in[7];
    const float* w22  = (const float*)d_in[8];
    const float* b22  = (const float*)d_in[9];
    const float* p1w1 = (const float*)d_in[10];
    const float* p1b1 = (const float*)d_in[11];
    const float* p1w2 = (const float*)d_in[12];
    const float* p1b2 = (const float*)d_in[13];
    const float* p2w1 = (const float*)d_in[14];
    const float* p2b1 = (const float*)d_in[15];
    const float* p2w2 = (const float*)d_in[16];
    const float* p2b2 = (const float*)d_in[17];
    const float* cw   = (const float*)d_in[18];
    const float* cb   = (const float*)d_in[19];
    float* out = (float*)d_out;

    const size_t NBH = (size_t)B * N * H;            // 262144
    const size_t BIG = (size_t)N * N * H;            // 1,048,576

    float* part2 = (float*)d_ws;                     // NBH
    float* emb1  = part2 + NBH;                      // B*H
    float* emb2  = emb1 + (size_t)B * H;             // B*H (layout slot)
    bfu* U1   = (bfu*)(emb2 + (size_t)B * H);        // NBH each
    bfu* V1   = U1 + NBH;
    bfu* U2   = V1 + NBH;
    bfu* V2   = U2 + NBH;
    bfu* h2g  = V2 + NBH;                            // NBH
    bfu* acb  = h2g + NBH;                           // B*N*N
    bfu* adjf = acb + (size_t)B * N * N;             // B*N*N
    bfu* w11t = adjf + (size_t)B * N * N;
    bfu* w12t = w11t + 32 * 64;
    bfu* w21t = w12t + 32 * 64;
    bfu* w22t = w21t + 64 * 64;
    bfu* u1t  = w22t + 64 * 64;
    bfu* v1t  = u1t + 64 * 64;
    bfu* u2t  = v1t + 64 * 64;
    bfu* v2t  = u2t + 64 * 64;
    bfu* W1t  = v2t + 64 * 64;
    bfu* W2t  = W1t + 64 * 64;
    bfu* bigBase = W2t + 64 * 64;
    size_t smallBytes = (char*)bigBase - (char*)d_ws;

    int CB = B;
    while (CB > 1 && smallBytes + 2ull * CB * BIG * sizeof(bfu) > ws_size) CB >>= 1;
    bfu* T1 = bigBase;
    bfu* T2 = T1 + (size_t)CB * BIG;

    // fused prep (512 adj blocks + 10 weight blocks)
    {
        WT p;
        const float* srcs[10] = {w11, w12, w21, w22,
                                 p1w1, p1w1 + 64 * H, p1w2, p1w2 + 64 * H,
                                 p2w1, p2w2};
        bfu* dsts[10] = {w11t, w12t, w21t, w22t, u1t, v1t, u2t, v2t, W1t, W2t};
        int Ks[10] = {32, 32, 64, 64, 64, 64, 64, 64, 64, 64};
        for (int q = 0; q < 10; ++q) { p.src[q] = srcs[q]; p.dst[q] = dsts[q]; p.K[q] = Ks[q]; }
        prep_all<<<dim3(512 + 10), 256, 0, stream>>>(adj, acb, adjf, p);
    }
    // front-end: GNN layers + emb1 + h2
    gnn_front<<<dim3(B), 256, 0, stream>>>(x, adjf, w11t, b11, w12t, b12,
                                           w21t, b21, w22t, b22, h2g, emb1);
    // U/V projections, 4x parallel
    uv_proj<<<dim3(B * 4), 256, 0, stream>>>(h2g, u1t, v1t, u2t, v2t, U1, V1, U2, V2);
    // pair stages
    for (int b0 = 0; b0 < B; b0 += CB) {
        dim3 cg(CB * N);
        t1_mfma<<<cg, 256, 0, stream>>>(U2, V2, acb, p1w2 + 128 * H, p1b2, T1, b0);
        t2_fused<<<cg, 256, 0, stream>>>(U1, V1, acb, p1w1 + 128 * H, p1b1,
                                         T1, W2t, p2b2, T2, b0);
        combine2_fused<<<cg, 256, 0, stream>>>(U1, V1, acb, p1w1 + 128 * H, p1b1,
                                               T1, W1t, p2b1, T2, part2, b0);
    }
    // fused tail
    tail_kernel<<<dim3(B), 64, 0, stream>>>(part2, emb1, cw, cb, out);
}